// Round 1
// baseline (89.263 us; speedup 1.0000x reference)
//
#include <hip/hip_runtime.h>

// Hawkes log-likelihood, D=1024 dims, M=32768 events, BETA=1.
//
// lam_i = mu[d_i] + sum_{j<i} alpha[d_i,d_j] * exp(t_j - t_i).
// Chunk events into NC=512 chunks of C=64:
//   cross-chunk: exp(t_c0 - t_i) * dot(alpha[d_i,:], S_c)
//   in-chunk:    one lane-parallel predicated gather step (C == wave size)
// S_c via TWO-LEVEL dimension-parallel scan; level-1 histogram+scan fused in
// LDS; level-2 fixup S = Sl + Sg*cumdec fused into k_main's S load.
// Compensator: sum_i colsum[d_i] * (1 - exp(t_i - T)) fused into k_main.
//
// Lessons: R2 — same-cacheline global atomics serialize (~15ns) -> zero
// global atomics; grid-wide completion counters rejected for the same
// reason. R5 — single-block LDS-atomic histogram = 43us on one CU. R6 —
// DEEP dependent-chain roles must not be merged (regalloc pessimization);
// SHALLOW roles are safe (R11's k_mid verified). R9 — wide colred. R10 —
// bf16 alpha. R11 — 8 blocks/chunk k_main + k_mid merge. R12 — k_prep and
// k_fused merged into k1 (4 dispatches total).
// R13 (this round): top-5 rocprof dispatches are all 256MB harness poison
// fills at 42.5us each (2x42.6 = 85.2us of the 89us total) -> our 4 kernels
// are only ~3.8us. Shave them: k_main now ONE 512-thread block per chunk
// (was 8x256), cutting Sl+Sg refetch 32MB->4MB and grid 4096->512; float4
// S-fixup load; k_final 2-barrier shfl reduce. Discriminates fill-floor
// hypothesis: H1 -> dur ~87; H2 (fills untimed) -> big drop.
//
// ws floats: ab(bf16)[D*D] | Sl[NC*D] | mu[D] | colsum[D] | P[256*D] |
//            llp[NC] | compp[NC] | A[NG*D] | Sg[NG*D] | cumdec[NC]  (~5.5MB)

#define D 1024
#define M 32768
#define C 64
#define NC (M / C)   /* 512 */
#define NG 16        /* scan groups */
#define GC (NC / NG) /* 32 chunks per group */
#define TMAXV 1000.0f
#define EPSMU 1e-6f
#define EPSLOG 1e-8f

__device__ __forceinline__ float softplus(float x) {
    return (x > 0.0f) ? (x + log1pf(__expf(-x))) : log1pf(__expf(x));
}

// round-to-nearest-even fp32 -> bf16 (inputs are positive finite)
__device__ __forceinline__ unsigned short f2bf(float x) {
    unsigned u = __float_as_uint(x);
    return (unsigned short)((u + 0x7FFFu + ((u >> 16) & 1u)) >> 16);
}
__device__ __forceinline__ float bf2f(unsigned short h) {
    return __uint_as_float(((unsigned)h) << 16);
}

// Stage 1, one kernel, disjoint block roles; ALL roles read only raw inputs:
//   b in [0,256):   softplus(alpha) 4-row tile -> bf16 ab + fp32 colsum partial P
//   b == 256:       mu = softplus(log_mu) + eps
//   b in [257,321): fused level-1: per-chunk LDS histogram + LDS scan
//                   (16 groups x 4 dim-slices; writes Sl prefix + aggregate A)
__global__ void k1(const float* __restrict__ t_ev, const int* __restrict__ marks,
                   const float* __restrict__ log_alpha, const float* __restrict__ log_mu,
                   unsigned short* __restrict__ ab, float* __restrict__ mu,
                   float* __restrict__ P, float* __restrict__ Sl, float* __restrict__ A) {
    __shared__ float Lh[GC * 256];  // 32 KB (fused role only)
    __shared__ float dec[GC];
    __shared__ float tns[GC];
    int t = threadIdx.x;
    int b = blockIdx.x;

    if (b < 256) {
        int r0 = b * 4;
        float4 cs = {0.f, 0.f, 0.f, 0.f};
        for (int r = 0; r < 4; ++r) {
            const float4* src = (const float4*)(log_alpha + (size_t)(r0 + r) * D);
            float4 v = src[t];
            float4 a;
            a.x = softplus(v.x);
            a.y = softplus(v.y);
            a.z = softplus(v.z);
            a.w = softplus(v.w);
            cs.x += a.x; cs.y += a.y; cs.z += a.z; cs.w += a.w;
            ushort4 h;
            h.x = f2bf(a.x); h.y = f2bf(a.y); h.z = f2bf(a.z); h.w = f2bf(a.w);
            ((ushort4*)(ab + (size_t)(r0 + r) * D))[t] = h;
        }
        ((float4*)(P + (size_t)b * D))[t] = cs;  // P[b][col], col = 4t+j
    } else if (b == 256) {
#pragma unroll
        for (int q = 0; q < 4; ++q) {
            int k = t + 256 * q;
            mu[k] = softplus(log_mu[k]) + EPSMU;
        }
    } else {
        int fb = b - 257;            // 0..63
        int g = fb >> 2, db = fb & 3;
#pragma unroll
        for (int q = 0; q < GC; ++q) Lh[q * 256 + t] = 0.0f;
        if (t < GC) {
            int gc = g * GC + t;
            float tn = (gc + 1 < NC) ? t_ev[(gc + 1) * C] : t_ev[M - 1];
            tns[t] = tn;
            dec[t] = (gc + 1 < NC) ? __expf(t_ev[gc * C] - tn) : 1.0f;
        }
        __syncthreads();
        int base = g * (GC * C);  // 2048 events per group
#pragma unroll
        for (int it = 0; it < 8; ++it) {
            int e = it * 256 + t;
            float te = t_ev[base + e];
            int m = marks[base + e];
            int lc = e >> 6;
            int ml = m - db * 256;
            if ((unsigned)ml < 256u) atomicAdd(&Lh[lc * 256 + ml], __expf(te - tns[lc]));
        }
        __syncthreads();
        int k = db * 256 + t;
        float S = 0.0f;
        for (int lc = 0; lc < GC; ++lc) {
            Sl[(size_t)(g * GC + lc) * D + k] = S;
            S = S * dec[lc] + Lh[lc * 256 + t];
        }
        A[(size_t)g * D + k] = S;
    }
}

// Merged mid-stage, 9 blocks x 1024 threads (both roles SHALLOW):
//   blocks 0..7: reduce P[256][D] -> colsum (128 cols/block, 8 segs x 32 rows)
//   block 8:     level-2 scan over 16 group aggregates + per-chunk cumdec
__global__ void k_mid(const float* __restrict__ P, float* __restrict__ colsum,
                      const float* __restrict__ t_ev, const float* __restrict__ A,
                      float* __restrict__ Sg, float* __restrict__ cumdec) {
    int t = threadIdx.x;
    if (blockIdx.x < 8) {
        __shared__ float red[8][128];
        int colL = t & 127, seg = t >> 7;  // 8 segs x 128 cols
        int col = blockIdx.x * 128 + colL;
        float s = 0.0f;
#pragma unroll
        for (int j = 0; j < 32; ++j)
            s += P[(size_t)(seg * 32 + j) * D + col];
        red[seg][colL] = s;
        __syncthreads();
        if (t < 128) {
            float v = 0.0f;
#pragma unroll
            for (int k = 0; k < 8; ++k) v += red[k][t];
            colsum[blockIdx.x * 128 + t] = v;
        }
    } else {
        __shared__ float dec[NC];
        __shared__ float Pg[NG];
        if (t < NC)
            dec[t] = (t + 1 < NC) ? __expf(t_ev[t * C] - t_ev[(t + 1) * C]) : 1.0f;
        __syncthreads();
        if (t < NC) {
            int g = t >> 5, r = t & 31;
            float p = 1.0f;
            for (int j = 0; j < r; ++j) p *= dec[g * GC + j];
            cumdec[t] = p;
            if (r == GC - 1) Pg[g] = p * dec[t];
        }
        __syncthreads();
        float a[NG];
#pragma unroll
        for (int g2 = 0; g2 < NG; ++g2) a[g2] = A[(size_t)g2 * D + t];
        float S = 0.0f;
#pragma unroll
        for (int g2 = 0; g2 < NG; ++g2) {
            Sg[(size_t)g2 * D + t] = S;
            S = S * Pg[g2] + a[g2];
        }
    }
}

// main: ONE 512-thread block per chunk (8 waves x 8 events), fused scan
// fixup + compensator. alpha read as bf16. Per-block partials, no global
// atomics. S fixup loaded once per chunk (was 8x) via float4.
__launch_bounds__(512)
__global__ void k_main(const float* __restrict__ t_ev, const int* __restrict__ marks,
                       const unsigned short* __restrict__ ab, const float* __restrict__ mu,
                       const float* __restrict__ colsum, const float* __restrict__ Sl,
                       const float* __restrict__ Sg, const float* __restrict__ cumdec,
                       float* __restrict__ llp, float* __restrict__ compp) {
    __shared__ float S_lds[D];
    __shared__ float t_lds[C];
    __shared__ int d_lds[C];
    __shared__ float red_ll[8], red_cm[8];
    int t = threadIdx.x;
    int c = blockIdx.x;
    int g = c >> 5;
    float cd = cumdec[c];
    if (t < 256) {
        float4 a = ((const float4*)(Sl + (size_t)c * D))[t];
        float4 b = ((const float4*)(Sg + (size_t)g * D))[t];
        float4 s;
        s.x = a.x + b.x * cd;
        s.y = a.y + b.y * cd;
        s.z = a.z + b.z * cd;
        s.w = a.w + b.w * cd;
        ((float4*)S_lds)[t] = s;
    } else if (t < 320) {
        int e = t - 256;
        t_lds[e] = t_ev[c * C + e];
    } else if (t < 384) {
        int e = t - 320;
        d_lds[e] = marks[c * C + e];
    }
    __syncthreads();
    int wave = t >> 6, lane = t & 63;
    float t0 = t_lds[0];
    float ll_acc = 0.0f, comp_acc = 0.0f;
#pragma unroll
    for (int k = 0; k < 8; ++k) {
        int i = wave * 8 + k;
        int row = d_lds[i];
        float ti = t_lds[i];
        float mu_r = mu[row];
        float cs_r = colsum[row];
        const uint4* arow = (const uint4*)(ab + (size_t)row * D);
        float acc_dot = 0.0f;
#pragma unroll
        for (int u = 0; u < 2; ++u) {
            uint4 pk = arow[2 * lane + u];  // 8 bf16: cols 16*lane+8u .. +7
            const float4* sp = (const float4*)(S_lds + 16 * lane + 8 * u);
            float4 s0 = sp[0], s1 = sp[1];
            acc_dot += __uint_as_float(pk.x << 16) * s0.x
                     + __uint_as_float(pk.x & 0xFFFF0000u) * s0.y
                     + __uint_as_float(pk.y << 16) * s0.z
                     + __uint_as_float(pk.y & 0xFFFF0000u) * s0.w
                     + __uint_as_float(pk.z << 16) * s1.x
                     + __uint_as_float(pk.z & 0xFFFF0000u) * s1.y
                     + __uint_as_float(pk.w << 16) * s1.z
                     + __uint_as_float(pk.w & 0xFFFF0000u) * s1.w;
        }
        float part = acc_dot * __expf(t0 - ti);
        if (lane < i) {
            part += bf2f(ab[(size_t)row * D + d_lds[lane]]) * __expf(t_lds[lane] - ti);
        }
#pragma unroll
        for (int off = 32; off > 0; off >>= 1) part += __shfl_xor(part, off);
        if (lane == 0) {
            ll_acc += __logf(mu_r + part + EPSLOG);
            comp_acc += cs_r * (1.0f - __expf(ti - TMAXV));
        }
    }
    if (lane == 0) {
        red_ll[wave] = ll_acc;
        red_cm[wave] = comp_acc;
    }
    __syncthreads();
    if (t == 0) {
        float a = 0.0f, b = 0.0f;
#pragma unroll
        for (int w = 0; w < 8; ++w) { a += red_ll[w]; b += red_cm[w]; }
        llp[c] = a;
        compp[c] = b;
    }
}

// final: out = sum(llp) - (T*sum(mu) + sum(compp)). 1 block, 1024 threads,
// 1 barrier: per-thread fold -> wave shfl reduce -> 16-way cross-wave.
__global__ void k_final(const float* __restrict__ llp, const float* __restrict__ compp,
                        const float* __restrict__ mu, float* __restrict__ out) {
    __shared__ float acc[16];
    int t = threadIdx.x;
    float x = -TMAXV * mu[t];
    if (t < NC) x += llp[t] - compp[t];
#pragma unroll
    for (int off = 32; off > 0; off >>= 1) x += __shfl_xor(x, off);
    int wave = t >> 6, lane = t & 63;
    if (lane == 0) acc[wave] = x;
    __syncthreads();
    if (t < 16) {
        float v = acc[t];
#pragma unroll
        for (int off = 8; off > 0; off >>= 1) v += __shfl_xor(v, off, 16);
        if (t == 0) out[0] = v;
    }
}

extern "C" void kernel_launch(void* const* d_in, const int* in_sizes, int n_in,
                              void* d_out, int out_size, void* d_ws, size_t ws_size,
                              hipStream_t stream) {
    const float* t_ev = (const float*)d_in[0];
    const int* marks = (const int*)d_in[1];
    const float* log_mu = (const float*)d_in[2];
    const float* log_alpha = (const float*)d_in[3];
    float* out = (float*)d_out;

    float* w = (float*)d_ws;
    unsigned short* ab = (unsigned short*)w;        // D*D bf16 = D*D/2 floats
    float* Sl = w + (size_t)D * D / 2;              // NC*D
    float* mu = Sl + (size_t)NC * D;                // D
    float* colsum = mu + D;                         // D
    float* P = colsum + D;                          // 256*D
    float* llp = P + (size_t)256 * D;               // NC
    float* compp = llp + NC;                        // NC
    float* A = compp + NC;                          // NG*D
    float* Sg = A + (size_t)NG * D;                 // NG*D
    float* cumdec = Sg + (size_t)NG * D;            // NC

    k1<<<321, 256, 0, stream>>>(t_ev, marks, log_alpha, log_mu, ab, mu, P, Sl, A);
    k_mid<<<9, 1024, 0, stream>>>(P, colsum, t_ev, A, Sg, cumdec);
    k_main<<<NC, 512, 0, stream>>>(t_ev, marks, ab, mu, colsum, Sl, Sg, cumdec, llp, compp);
    k_final<<<1, 1024, 0, stream>>>(llp, compp, mu, out);
}